// Round 1
// baseline (112.685 us; speedup 1.0000x reference)
//
#include <hip/hip_runtime.h>

// VQ-VAE vector quantizer forward, MI355X / gfx950.
// latents [131072 x 64] fp32, codebook [1024 x 64] fp32.
// out[0 .. 8388607] = codebook[argmin ||x - c||^2]   (== q_st numerically)
// out[8388608]      = 1.25 * mean((q - x)^2)         (== vq_loss)

#define NROWS (32 * 4096)          // 131072
#define KC 1024
#define DD 64
#define LSTRIDE 72                 // 64 + 8 pad: breaks LDS bank aliasing for B-frag reads
#define OUT_LOSS ((size_t)NROWS * DD)  // 8388608

typedef __attribute__((ext_vector_type(8))) short short8;
typedef __attribute__((ext_vector_type(4))) short short4v;
typedef __attribute__((ext_vector_type(4))) float float4v;

static __device__ __forceinline__ short f2bf(float f) {
    // round-to-nearest-even f32 -> bf16 (no NaNs in this data)
    unsigned u = __float_as_uint(f);
    u += 0x7fffu + ((u >> 16) & 1u);
    return (short)(u >> 16);
}
static __device__ __forceinline__ float bf2f(short h) {
    return __uint_as_float(((unsigned)(unsigned short)h) << 16);
}

__global__ __launch_bounds__(1024, 4)
void vq_kernel(const float* __restrict__ x, const float* __restrict__ cb,
               float* __restrict__ out)
{
    __shared__ short lds_cb[KC * LSTRIDE];   // 144 KiB bf16 codebook (padded rows)
    __shared__ float lds_cn2[KC];            // ||c||^2 per code
    __shared__ float lds_x2[512];            // ||x||^2 per block-local row
    __shared__ float lds_loss;

    const int tid = threadIdx.x;
    if (tid == 0) lds_loss = 0.f;

    // ---- Phase 1a: stage codebook fp32 -> bf16 LDS, coalesced float4 loads ----
    {
        const float4v* cb4 = (const float4v*)cb;
        #pragma unroll
        for (int i = 0; i < 16; ++i) {
            int e4 = tid + i * 1024;          // float4 index in [0, 16384)
            int row = e4 >> 4;                // 16 float4 per 64-elem row
            int col = (e4 & 15) * 4;
            float4v v = cb4[e4];
            short4v h;
            h[0] = f2bf(v[0]); h[1] = f2bf(v[1]);
            h[2] = f2bf(v[2]); h[3] = f2bf(v[3]);
            *(short4v*)&lds_cb[row * LSTRIDE + col] = h;   // 8B aligned
        }
    }
    __syncthreads();

    // ---- Phase 1b: ||c||^2 in fp32 from staged bf16 (one code per thread) ----
    {
        const short* cr = &lds_cb[tid * LSTRIDE];
        float s = 0.f;
        #pragma unroll 8
        for (int j = 0; j < 64; ++j) { float f = bf2f(cr[j]); s = fmaf(f, f, s); }
        lds_cn2[tid] = s;
    }
    __syncthreads();

    // ---- Phase 2: per-wave MFMA argmin over all 1024 codes ----
    const int lane    = tid & 63;
    const int wave    = tid >> 6;       // 0..15
    const int lanemod = lane & 15;
    const int quad    = lane >> 4;      // 0..3

    const int rowblock = blockIdx.x * 512;
    const int rowwave  = rowblock + wave * 32;   // this wave: 32 rows, 2 m-tiles of 16

    // A fragments: A[m = lane&15][k = quad*8 + j], k-halves 0..31 / 32..63.
    short8 afrag[2][2];
    #pragma unroll
    for (int t = 0; t < 2; ++t) {
        int row = rowwave + t * 16 + lanemod;
        const float* xr = x + (size_t)row * DD;
        float p = 0.f;
        #pragma unroll
        for (int kh = 0; kh < 2; ++kh) {
            float4v v0 = *(const float4v*)(xr + kh * 32 + quad * 8);
            float4v v1 = *(const float4v*)(xr + kh * 32 + quad * 8 + 4);
            p += v0[0]*v0[0] + v0[1]*v0[1] + v0[2]*v0[2] + v0[3]*v0[3]
               + v1[0]*v1[0] + v1[1]*v1[1] + v1[2]*v1[2] + v1[3]*v1[3];
            short8 a;
            a[0] = f2bf(v0[0]); a[1] = f2bf(v0[1]); a[2] = f2bf(v0[2]); a[3] = f2bf(v0[3]);
            a[4] = f2bf(v1[0]); a[5] = f2bf(v1[1]); a[6] = f2bf(v1[2]); a[7] = f2bf(v1[3]);
            afrag[t][kh] = a;
        }
        // sum ||x||^2 partials across the 4 quads (each quad holds 16 of 64 elems)
        p += __shfl_xor(p, 16);
        p += __shfl_xor(p, 32);
        if (quad == 0) lds_x2[wave * 32 + t * 16 + lanemod] = p;
    }

    float mins[2][4];
    int   mini[2][4];
    #pragma unroll
    for (int t = 0; t < 2; ++t)
        #pragma unroll
        for (int r = 0; r < 4; ++r) { mins[t][r] = 3.4e38f; mini[t][r] = 0; }

    #pragma unroll 2
    for (int n0 = 0; n0 < KC; n0 += 16) {
        int n = n0 + lanemod;                 // this lane's tracked column
        float cn2 = lds_cn2[n];
        const short* bp = &lds_cb[n * LSTRIDE];
        short8 b0 = *(const short8*)(bp + quad * 8);        // k 0..31
        short8 b1 = *(const short8*)(bp + 32 + quad * 8);   // k 32..63
        #pragma unroll
        for (int t = 0; t < 2; ++t) {
            float4v acc = {0.f, 0.f, 0.f, 0.f};
            acc = __builtin_amdgcn_mfma_f32_16x16x32_bf16(afrag[t][0], b0, acc, 0, 0, 0);
            acc = __builtin_amdgcn_mfma_f32_16x16x32_bf16(afrag[t][1], b1, acc, 0, 0, 0);
            #pragma unroll
            for (int r = 0; r < 4; ++r) {
                float s = fmaf(-2.f, acc[r], cn2);   // ||c||^2 - 2 x.c
                bool lt = s < mins[t][r];
                mins[t][r] = lt ? s : mins[t][r];
                mini[t][r] = lt ? n : mini[t][r];
            }
        }
    }

    // ---- argmin reduce across the 16 lanes sharing each row group ----
    #pragma unroll
    for (int t = 0; t < 2; ++t)
        #pragma unroll
        for (int r = 0; r < 4; ++r) {
            float s = mins[t][r];
            int   i = mini[t][r];
            #pragma unroll
            for (int off = 1; off < 16; off <<= 1) {
                float s2 = __shfl_xor(s, off);
                int   i2 = __shfl_xor(i, off);
                if (s2 < s || (s2 == s && i2 < i)) { s = s2; i = i2; }
            }
            mins[t][r] = s;
            mini[t][r] = i;
        }

    // ---- gather q (fp32, L2-resident codebook) + write + loss ----
    float lsum = 0.f;
    #pragma unroll
    for (int t = 0; t < 2; ++t)
        #pragma unroll
        for (int r = 0; r < 4; ++r) {
            int rowl = wave * 32 + t * 16 + quad * 4 + r;   // block-local row
            int row  = rowblock + rowl;
            int nb   = mini[t][r];                          // uniform across the 16 lanes
            float4v q = *(const float4v*)(cb + (size_t)nb * DD + lanemod * 4);
            *(float4v*)(out + (size_t)row * DD + lanemod * 4) = q;  // 256B/row coalesced
            if (lanemod == 0) lsum += lds_x2[rowl] + mins[t][r];    // = min ||x-c||^2
        }
    if (lanemod == 0) atomicAdd(&lds_loss, lsum);
    __syncthreads();
    if (tid == 0)
        atomicAdd(out + OUT_LOSS, lds_loss * (1.25f / (float)OUT_LOSS));
}

extern "C" void kernel_launch(void* const* d_in, const int* in_sizes, int n_in,
                              void* d_out, int out_size, void* d_ws, size_t ws_size,
                              hipStream_t stream) {
    (void)in_sizes; (void)n_in; (void)out_size; (void)d_ws; (void)ws_size;
    const float* x  = (const float*)d_in[0];
    const float* cb = (const float*)d_in[1];
    float* out = (float*)d_out;
    // loss slot is poisoned 0xAA before every launch -> zero it on-stream
    hipMemsetAsync((char*)d_out + OUT_LOSS * sizeof(float), 0, sizeof(float), stream);
    vq_kernel<<<dim3(NROWS / 512), dim3(1024), 0, stream>>>(x, cb, out);
}

// Round 2
// 112.296 us; speedup vs baseline: 1.0035x; 1.0035x over previous
//
#include <hip/hip_runtime.h>

// VQ-VAE vector quantizer forward, MI355X / gfx950.
// latents [131072 x 64] fp32, codebook [1024 x 64] fp32.
// out[0 .. 8388607] = codebook[argmin ||x - c||^2]
// out[8388608]      = 1.25 * mean((q - x)^2)
//
// R1 changes vs R0:
//  - 512-thread blocks, 4 m-tiles/wave: halves per-CU ds_read_b128 count
//  - codebook staged in B-fragment order -> sequential conflict-free b128 reads
//  - -0.5||c||^2 folded into MFMA C operand; argmin via index-packed-in-mantissa
//    (v_and_or_b32 + v_max_f32 = 2 VALU/score, was 4)
//  - ||c||^2 computed in-register during staging (phase-1b LDS reads eliminated)

#define NROWS (32 * 4096)              // 131072
#define KC 1024
#define DD 64
#define OUT_LOSS ((size_t)NROWS * DD)  // 8388608

typedef __attribute__((ext_vector_type(8))) short short8;
typedef __attribute__((ext_vector_type(4))) float float4v;

static __device__ __forceinline__ short f2bf(float f) {
    // round-to-nearest-even f32 -> bf16 (no NaNs in this data)
    unsigned u = __float_as_uint(f);
    u += 0x7fffu + ((u >> 16) & 1u);
    return (short)(u >> 16);
}

__global__ __launch_bounds__(512, 2)
void vq_kernel(const float* __restrict__ x, const float* __restrict__ cb,
               float* __restrict__ out)
{
    // B-fragment-ordered bf16 codebook: for n-tile T (16 codes) and k-half h,
    // lane l's chunk (8 bf16 = code T*16+(l&15), dims h*32+(l>>4)*8 ..+8)
    // lives at ((T*2+h)*64 + l) * 8 shorts -> ds_read_b128 at base + lane*16B.
    __shared__ short lds_cb[KC * DD];      // 128 KiB
    __shared__ float lds_cn2h[KC];         // -0.5 * ||c||^2 (fp32)
    __shared__ float lds_x2[512];          // ||x||^2 per block-local row
    __shared__ float lds_loss;

    const int tid     = threadIdx.x;
    const int lane    = tid & 63;
    const int wave    = tid >> 6;          // 0..7
    const int lanemod = lane & 15;
    const int quad    = lane >> 4;         // 0..3

    if (tid == 0) lds_loss = 0.f;

    const int rowblock = blockIdx.x * 512;
    const int rowwave  = rowblock + wave * 64;   // this wave: 64 rows, 4 m-tiles

    // ---- A fragments first (global loads issued early; overlap with staging) ----
    // A[m = lane&15][k = quad*8 + j], k-halves 0..31 / 32..63.
    short8 afrag[4][2];
    #pragma unroll
    for (int t = 0; t < 4; ++t) {
        const int row = rowwave + t * 16 + lanemod;
        const float* xr = x + (size_t)row * DD;
        float p = 0.f;
        #pragma unroll
        for (int kh = 0; kh < 2; ++kh) {
            float4v v0 = *(const float4v*)(xr + kh * 32 + quad * 8);
            float4v v1 = *(const float4v*)(xr + kh * 32 + quad * 8 + 4);
            p += v0[0]*v0[0] + v0[1]*v0[1] + v0[2]*v0[2] + v0[3]*v0[3]
               + v1[0]*v1[0] + v1[1]*v1[1] + v1[2]*v1[2] + v1[3]*v1[3];
            short8 a;
            a[0] = f2bf(v0[0]); a[1] = f2bf(v0[1]); a[2] = f2bf(v0[2]); a[3] = f2bf(v0[3]);
            a[4] = f2bf(v1[0]); a[5] = f2bf(v1[1]); a[6] = f2bf(v1[2]); a[7] = f2bf(v1[3]);
            afrag[t][kh] = a;
        }
        // quads hold disjoint 16-elem k-slices of the same row -> sum over quads
        p += __shfl_xor(p, 16);
        p += __shfl_xor(p, 32);
        if (quad == 0) lds_x2[wave * 64 + t * 16 + lanemod] = p;
    }

    // ---- stage codebook: each thread owns codes tid and tid+512 ----
    #pragma unroll
    for (int c = 0; c < 2; ++c) {
        const int n = tid + c * 512;
        const int T = n >> 4, j = n & 15;
        const float4v* src = (const float4v*)(cb + (size_t)n * DD);
        float s2 = 0.f;
        #pragma unroll
        for (int g = 0; g < 8; ++g) {                 // 8-dim chunk g
            float4v v0 = src[g * 2 + 0];
            float4v v1 = src[g * 2 + 1];
            s2 += v0[0]*v0[0] + v0[1]*v0[1] + v0[2]*v0[2] + v0[3]*v0[3]
                + v1[0]*v1[0] + v1[1]*v1[1] + v1[2]*v1[2] + v1[3]*v1[3];
            short8 hc;
            hc[0] = f2bf(v0[0]); hc[1] = f2bf(v0[1]); hc[2] = f2bf(v0[2]); hc[3] = f2bf(v0[3]);
            hc[4] = f2bf(v1[0]); hc[5] = f2bf(v1[1]); hc[6] = f2bf(v1[2]); hc[7] = f2bf(v1[3]);
            const int h = g >> 2, q = g & 3;
            *(short8*)&lds_cb[((T * 2 + h) * 64 + q * 16 + j) * 8] = hc;
        }
        lds_cn2h[n] = -0.5f * s2;
    }
    __syncthreads();

    // ---- main loop: sweep 64 n-tiles, track max of (x.c - 0.5||c||^2) ----
    // score packed as float with 10-bit code index in low mantissa bits.
    const float NEGINF = __uint_as_float(0xFF800000u);
    float packed[4][4];
    #pragma unroll
    for (int t = 0; t < 4; ++t)
        #pragma unroll
        for (int r = 0; r < 4; ++r) packed[t][r] = NEGINF;

    #pragma unroll 2
    for (int T = 0; T < KC / 16; ++T) {
        const short* bbase = &lds_cb[T * 1024];
        short8 b0 = *(const short8*)(bbase + lane * 8);          // k 0..31
        short8 b1 = *(const short8*)(bbase + 512 + lane * 8);    // k 32..63
        const float    ch   = lds_cn2h[T * 16 + lanemod];        // -0.5||c||^2
        const unsigned nidx = (unsigned)(T * 16 + lanemod);
        #pragma unroll
        for (int t = 0; t < 4; ++t) {
            float4v acc = {ch, ch, ch, ch};                      // C = -0.5||c||^2
            acc = __builtin_amdgcn_mfma_f32_16x16x32_bf16(afrag[t][0], b0, acc, 0, 0, 0);
            acc = __builtin_amdgcn_mfma_f32_16x16x32_bf16(afrag[t][1], b1, acc, 0, 0, 0);
            #pragma unroll
            for (int r = 0; r < 4; ++r) {
                float pk = __uint_as_float((__float_as_uint(acc[r]) & 0xFFFFFC00u) | nidx);
                packed[t][r] = fmaxf(packed[t][r], pk);          // v_and_or + v_max
            }
        }
    }

    // ---- argmax reduce across the 16 lanemod lanes of each quad group ----
    #pragma unroll
    for (int t = 0; t < 4; ++t)
        #pragma unroll
        for (int r = 0; r < 4; ++r) {
            float p = packed[t][r];
            #pragma unroll
            for (int off = 1; off < 16; off <<= 1)
                p = fmaxf(p, __shfl_xor(p, off));
            packed[t][r] = p;
        }

    // ---- gather q (fp32, L2-resident codebook) + write + loss ----
    float lsum = 0.f;
    #pragma unroll
    for (int t = 0; t < 4; ++t)
        #pragma unroll
        for (int r = 0; r < 4; ++r) {
            const int rowl = wave * 64 + t * 16 + quad * 4 + r;  // block-local row
            const int row  = rowblock + rowl;
            const unsigned pu = __float_as_uint(packed[t][r]);
            const int   nb   = (int)(pu & 1023u);                // winning code
            const float mval = __uint_as_float(pu & 0xFFFFFC00u);// max(x.c - .5||c||^2)
            float4v q = *(const float4v*)(cb + (size_t)nb * DD + lanemod * 4);
            *(float4v*)(out + (size_t)row * DD + lanemod * 4) = q;  // 256B/row
            if (lanemod == 0) lsum += lds_x2[rowl] - 2.f * mval;    // = min||x-c||^2
        }
    if (lanemod == 0) atomicAdd(&lds_loss, lsum);
    __syncthreads();
    if (tid == 0)
        atomicAdd(out + OUT_LOSS, lds_loss * (1.25f / (float)OUT_LOSS));
}

extern "C" void kernel_launch(void* const* d_in, const int* in_sizes, int n_in,
                              void* d_out, int out_size, void* d_ws, size_t ws_size,
                              hipStream_t stream) {
    (void)in_sizes; (void)n_in; (void)out_size; (void)d_ws; (void)ws_size;
    const float* x  = (const float*)d_in[0];
    const float* cb = (const float*)d_in[1];
    float* out = (float*)d_out;
    // loss slot is poisoned 0xAA before every launch -> zero it on-stream
    hipMemsetAsync((char*)d_out + OUT_LOSS * sizeof(float), 0, sizeof(float), stream);
    vq_kernel<<<dim3(NROWS / 512), dim3(512), 0, stream>>>(x, cb, out);
}